// Round 3
// baseline (844.941 us; speedup 1.0000x reference)
//
#include <hip/hip_runtime.h>
#include <hip/hip_bf16.h>
#include <math.h>

#define N_CB   8
#define M_EMB  1024
#define D_EMB  128
#define H_LAT  64
#define B_SZ   256
#define L_PER  (B_SZ * H_LAT)                  /* 16384 rows per codebook */
#define TOTAL_X (B_SZ * N_CB * D_EMB * H_LAT)  /* 16,777,216 elements     */

/* d_out layout (floats): [z_q | loss | entropy | perplexity | indices] */
#define LOSS_OFF (TOTAL_X)
#define ENT_OFF  (TOTAL_X + 1)
#define PPL_OFF  (TOTAL_X + 2)
#define IDX_OFF  (TOTAL_X + 3)

/* ws layout (4-byte units):
 * e_sq[8192] | idx[131072] | counts[8192] | lossacc | flagcnt | flags[32768] */
#define WS_ESQ_OFF    0
#define WS_IDX_OFF    (8192)
#define WS_CNT_OFF    (8192 + 131072)
#define WS_LOSS_OFF   (8192 + 131072 + 8192)
#define WS_FCNT_OFF   (WS_LOSS_OFF + 1)
#define WS_FLAG_OFF   (WS_FCNT_OFF + 1)
#define FLAG_CAP      32768
#define TAU           1e-4f

__global__ void init_ws(int* __restrict__ counts, float* __restrict__ lossacc,
                        int* __restrict__ flagcnt) {
    int t = blockIdx.x * 256 + threadIdx.x;
    if (t < N_CB * M_EMB) counts[t] = 0;
    if (t == 0) { *lossacc = 0.f; *flagcnt = 0; }
}

/* one wave per embedding row: e_sq[n,m] = sum_d e^2 */
__global__ void esq_kernel(const float* __restrict__ e, float* __restrict__ esq) {
    int wave = (blockIdx.x * blockDim.x + threadIdx.x) >> 6;
    int lane = threadIdx.x & 63;
    if (wave >= N_CB * M_EMB) return;
    float2 v = reinterpret_cast<const float2*>(e + (size_t)wave * D_EMB)[lane];
    float s = v.x * v.x + v.y * v.y;
    #pragma unroll
    for (int off = 32; off; off >>= 1) s += __shfl_down(s, off);
    if (lane == 0) esq[wave] = s;
}

/* Fused distance-GEMM + argmin with second-min tracking (flags near-ties).
 * grid = 8 codebooks * 128 (pairs of b) = 1024 blocks, 256 threads. */
__launch_bounds__(256, 4)
__global__ void vq_argmin_kernel(const float* __restrict__ x,
                                 const float* __restrict__ emb,
                                 const float* __restrict__ esq,
                                 int*  __restrict__ idx_ws,
                                 int*  __restrict__ counts,
                                 int*  __restrict__ flagcnt,
                                 int*  __restrict__ flags,
                                 float* __restrict__ out)
{
    __shared__ float xs[32][128];   /* [d][row] */
    __shared__ float es[32][128];   /* [d][phys m], slot-swizzled */

    const int n  = blockIdx.x >> 7;
    const int b0 = (blockIdx.x & 127) << 1;
    const int t  = threadIdx.x;
    const int tx = t & 15;          /* m-group */
    const int ty = t >> 4;          /* row-group */

    float minv[8], min2[8];
    int   mini[8];
    #pragma unroll
    for (int i = 0; i < 8; i++) { minv[i] = INFINITY; min2[i] = INFINITY; mini[i] = 0; }

    const float* xbase  = x + (size_t)(b0 * N_CB + n) * D_EMB * H_LAT;
    const float* ebase  = emb + (size_t)n * M_EMB * D_EMB;
    const float* eqbase = esq + n * M_EMB;

    for (int mc = 0; mc < 8; ++mc) {
        float C[8][8];
        #pragma unroll
        for (int i = 0; i < 8; i++)
            #pragma unroll
            for (int j = 0; j < 8; j++) C[i][j] = 0.f;

        for (int dc = 0; dc < 4; ++dc) {
            __syncthreads();
            #pragma unroll
            for (int i = 0; i < 4; i++) {
                int f   = i * 256 + t;
                int d   = f >> 5;
                int rem = f & 31;
                int bb  = rem >> 4;
                int h4  = rem & 15;
                float4 v = *reinterpret_cast<const float4*>(
                    xbase + (size_t)bb * (N_CB * D_EMB * H_LAT)
                          + (size_t)(dc * 32 + d) * H_LAT + h4 * 4);
                *reinterpret_cast<float4*>(&xs[d][bb * 64 + h4 * 4]) = v;
            }
            #pragma unroll
            for (int i = 0; i < 4; i++) {
                int f  = i * 256 + t;
                int m  = f >> 3;
                int d4 = f & 7;
                float4 v = *reinterpret_cast<const float4*>(
                    ebase + (size_t)(mc * 128 + m) * D_EMB + dc * 32 + d4 * 4);
                int s     = m >> 2;
                int physs = (s >> 1) | ((s & 1) << 4);
                int col   = physs * 4 + (m & 3);
                es[d4 * 4 + 0][col] = v.x;
                es[d4 * 4 + 1][col] = v.y;
                es[d4 * 4 + 2][col] = v.z;
                es[d4 * 4 + 3][col] = v.w;
            }
            __syncthreads();
            #pragma unroll
            for (int d = 0; d < 32; ++d) {
                float4 a0  = *reinterpret_cast<const float4*>(&xs[d][ty * 8]);
                float4 a1  = *reinterpret_cast<const float4*>(&xs[d][ty * 8 + 4]);
                float4 b0v = *reinterpret_cast<const float4*>(&es[d][tx * 4]);
                float4 b1v = *reinterpret_cast<const float4*>(&es[d][64 + tx * 4]);
                float a[8]  = {a0.x, a0.y, a0.z, a0.w, a1.x, a1.y, a1.z, a1.w};
                float bv[8] = {b0v.x, b0v.y, b0v.z, b0v.w, b1v.x, b1v.y, b1v.z, b1v.w};
                #pragma unroll
                for (int i = 0; i < 8; i++)
                    #pragma unroll
                    for (int j = 0; j < 8; j++)
                        C[i][j] = fmaf(a[i], bv[j], C[i][j]);
            }
        }
        float4 eqa = *reinterpret_cast<const float4*>(eqbase + mc * 128 + tx * 8);
        float4 eqb = *reinterpret_cast<const float4*>(eqbase + mc * 128 + tx * 8 + 4);
        float eq[8] = {eqa.x, eqa.y, eqa.z, eqa.w, eqb.x, eqb.y, eqb.z, eqb.w};
        #pragma unroll
        for (int i = 0; i < 8; i++) {
            #pragma unroll
            for (int j = 0; j < 8; j++) {
                int   m    = mc * 128 + tx * 8 + j;
                float dist = eq[j] - 2.f * C[i][j];
                if (dist < minv[i]) { min2[i] = minv[i]; minv[i] = dist; mini[i] = m; }
                else if (dist < min2[i]) min2[i] = dist;
            }
        }
    }

    #pragma unroll
    for (int i = 0; i < 8; i++) {
        float v1 = minv[i], v2 = min2[i];
        int   i1 = mini[i];
        #pragma unroll
        for (int off = 1; off < 16; off <<= 1) {
            float o1 = __shfl_xor(v1, off);
            float o2 = __shfl_xor(v2, off);
            int   oi = __shfl_xor(i1, off);
            float nv2 = fminf(fmaxf(v1, o1), fminf(v2, o2));
            if (o1 < v1 || (o1 == v1 && oi < i1)) { v1 = o1; i1 = oi; }
            v2 = nv2;
        }
        if (tx == 0) {
            int r  = ty * 8 + i;
            int bb = r >> 6;
            int h  = r & 63;
            int b  = b0 + bb;
            int l  = b * H_LAT + h;
            idx_ws[n * L_PER + l] = i1;
            atomicAdd(&counts[n * M_EMB + i1], 1);
            out[IDX_OFF + (b * N_CB + n) * H_LAT + h] = (float)i1;
            if (v2 - v1 < TAU) {               /* near-tie: np-exact fixup */
                int slot = atomicAdd(flagcnt, 1);
                if (slot < FLAG_CAP) flags[slot] = (n << 14) | l;
            }
        }
    }
}

/* numpy-fp32-semantics re-argmin for flagged near-tie rows.
 * Emulates np: dist = fl(fl(e_sq + x_sq) - 2*cross), cross via the einsum
 * SOP inner loop: 4 stripe accumulators (i mod 4), mul & add separately
 * rounded, combined (a0+a1)+(a2+a3). x_sq: any accurate fp32 (shift-inv). */
__global__ void fixup_np_kernel(const float* __restrict__ x,
                                const float* __restrict__ emb,
                                const float* __restrict__ esq,
                                const int* __restrict__ flags,
                                const int* __restrict__ flagcnt,
                                int* __restrict__ idx_ws,
                                int* __restrict__ counts,
                                float* __restrict__ out)
{
    __shared__ float xrow[128];
    __shared__ float xsq_sh;
    __shared__ float bestv[4];
    __shared__ int   besti[4];
    int cnt = *flagcnt;
    if (cnt > FLAG_CAP) cnt = FLAG_CAP;
    int t = threadIdx.x;
    int lane = t & 63, w = t >> 6;

    for (int f = blockIdx.x; f < cnt; f += gridDim.x) {
        int key = flags[f];
        int n = key >> 14;
        int l = key & (L_PER - 1);
        int b = l >> 6, h = l & 63;
        if (t < 128)
            xrow[t] = x[(size_t)(b * N_CB + n) * (D_EMB * H_LAT) + (size_t)t * H_LAT + h];
        __syncthreads();
        if (t == 0) {
            double s = 0.0;
            for (int d = 0; d < 128; d++) { double v = (double)xrow[d]; s += v * v; }
            xsq_sh = (float)s;
        }
        __syncthreads();
        float xsq = xsq_sh;

        float bv = INFINITY; int bi = 0x7fffffff;
        const float* eb  = emb + (size_t)n * M_EMB * D_EMB;
        const float* eqn = esq + n * M_EMB;
        for (int m = t; m < M_EMB; m += 256) {
            const float* er = eb + (size_t)m * D_EMB;
            float a0 = 0.f, a1 = 0.f, a2 = 0.f, a3 = 0.f;
            #pragma unroll 8
            for (int i = 0; i < 128; i += 4) {
                a0 = __fadd_rn(a0, __fmul_rn(xrow[i + 0], er[i + 0]));
                a1 = __fadd_rn(a1, __fmul_rn(xrow[i + 1], er[i + 1]));
                a2 = __fadd_rn(a2, __fmul_rn(xrow[i + 2], er[i + 2]));
                a3 = __fadd_rn(a3, __fmul_rn(xrow[i + 3], er[i + 3]));
            }
            float cr   = __fadd_rn(__fadd_rn(a0, a1), __fadd_rn(a2, a3));
            float t1   = __fadd_rn(eqn[m], xsq);
            float dist = __fadd_rn(t1, __fmul_rn(-2.f, cr));
            if (dist < bv || (dist == bv && m < bi)) { bv = dist; bi = m; }
        }
        #pragma unroll
        for (int off = 1; off < 64; off <<= 1) {
            float ov = __shfl_xor(bv, off);
            int   oi = __shfl_xor(bi, off);
            if (ov < bv || (ov == bv && oi < bi)) { bv = ov; bi = oi; }
        }
        if (lane == 0) { bestv[w] = bv; besti[w] = bi; }
        __syncthreads();
        if (t == 0) {
            for (int w2 = 1; w2 < 4; w2++)
                if (bestv[w2] < bv || (bestv[w2] == bv && besti[w2] < bi)) {
                    bv = bestv[w2]; bi = besti[w2];
                }
            int old = idx_ws[n * L_PER + l];
            if (old != bi) {
                idx_ws[n * L_PER + l] = bi;
                atomicSub(&counts[n * M_EMB + old], 1);
                atomicAdd(&counts[n * M_EMB + bi], 1);
                out[IDX_OFF + (b * N_CB + n) * H_LAT + h] = (float)bi;
            }
        }
        __syncthreads();
    }
}

/* z_q scatter + commitment-loss accumulation. One float4 (4 h) per thread. */
__global__ void scatter_loss_kernel(const float* __restrict__ x,
                                    const float* __restrict__ emb,
                                    const int* __restrict__ idx_ws,
                                    float* __restrict__ out,
                                    float* __restrict__ lossacc)
{
    int o4 = blockIdx.x * 256 + threadIdx.x;
    int h4 = o4 & 15;
    int d  = (o4 >> 4) & 127;
    int n  = (o4 >> 11) & 7;
    int b  = o4 >> 14;

    float4 xv = reinterpret_cast<const float4*>(x)[o4];
    int4 iv = *reinterpret_cast<const int4*>(idx_ws + n * L_PER + b * H_LAT + h4 * 4);
    const float* eb = emb + (size_t)n * M_EMB * D_EMB + d;
    float q0 = eb[(size_t)iv.x * D_EMB];
    float q1 = eb[(size_t)iv.y * D_EMB];
    float q2 = eb[(size_t)iv.z * D_EMB];
    float q3 = eb[(size_t)iv.w * D_EMB];
    reinterpret_cast<float4*>(out)[o4] = make_float4(q0, q1, q2, q3);

    float d0 = xv.x - q0, d1 = xv.y - q1, d2 = xv.z - q2, d3 = xv.w - q3;
    float s = d0 * d0 + d1 * d1 + d2 * d2 + d3 * d3;
    #pragma unroll
    for (int off = 32; off; off >>= 1) s += __shfl_down(s, off);
    __shared__ float wsum[4];
    int lane = threadIdx.x & 63, w = threadIdx.x >> 6;
    if (lane == 0) wsum[w] = s;
    __syncthreads();
    if (threadIdx.x == 0)
        atomicAdd(lossacc, wsum[0] + wsum[1] + wsum[2] + wsum[3]);
}

/* entropy / perplexity over usage histogram + final loss write. 1 block. */
__global__ void finish_kernel(const int* __restrict__ counts,
                              const float* __restrict__ lossacc,
                              float* __restrict__ out)
{
    __shared__ float red[16];
    int t = threadIdx.x;
    float entsum = 0.f, pplsum = 0.f;
    for (int n = 0; n < N_CB; n++) {
        float p = counts[n * M_EMB + t] * (1.f / L_PER);
        float s = p * logf(p + 1e-10f);
        #pragma unroll
        for (int off = 32; off; off >>= 1) s += __shfl_down(s, off);
        int lane = t & 63, w = t >> 6;
        if (lane == 0) red[w] = s;
        __syncthreads();
        if (t < 16) {
            float v = red[t];
            #pragma unroll
            for (int off = 8; off; off >>= 1) v += __shfl_down(v, off);
            if (t == 0) red[0] = v;
        }
        __syncthreads();
        float ent = -red[0];
        entsum += ent;
        pplsum += expf(ent);
        __syncthreads();
    }
    if (t == 0) {
        out[ENT_OFF]  = entsum * (1.f / N_CB);
        out[PPL_OFF]  = pplsum * (1.f / N_CB);
        out[LOSS_OFF] = 0.25f * (*lossacc) / (float)TOTAL_X;
    }
}

extern "C" void kernel_launch(void* const* d_in, const int* in_sizes, int n_in,
                              void* d_out, int out_size, void* d_ws, size_t ws_size,
                              hipStream_t stream)
{
    const float* x   = (const float*)d_in[0];
    const float* emb = (const float*)d_in[1];
    float* out = (float*)d_out;

    float* esq     = (float*)d_ws + WS_ESQ_OFF;
    int*   idx_ws  = (int*)d_ws + WS_IDX_OFF;
    int*   counts  = (int*)d_ws + WS_CNT_OFF;
    float* lossacc = (float*)d_ws + WS_LOSS_OFF;
    int*   flagcnt = (int*)d_ws + WS_FCNT_OFF;
    int*   flags   = (int*)d_ws + WS_FLAG_OFF;

    hipLaunchKernelGGL(init_ws, dim3(33), dim3(256), 0, stream, counts, lossacc, flagcnt);
    hipLaunchKernelGGL(esq_kernel, dim3(2048), dim3(256), 0, stream, emb, esq);
    hipLaunchKernelGGL(vq_argmin_kernel, dim3(1024), dim3(256), 0, stream,
                       x, emb, esq, idx_ws, counts, flagcnt, flags, out);
    hipLaunchKernelGGL(fixup_np_kernel, dim3(1024), dim3(256), 0, stream,
                       x, emb, esq, flags, flagcnt, idx_ws, counts, out);
    hipLaunchKernelGGL(scatter_loss_kernel, dim3(TOTAL_X / 4 / 256), dim3(256), 0, stream,
                       x, emb, idx_ws, out, lossacc);
    hipLaunchKernelGGL(finish_kernel, dim3(1), dim3(1024), 0, stream,
                       counts, lossacc, out);
}